// Round 1
// baseline (533.404 us; speedup 1.0000x reference)
//
#include <hip/hip_runtime.h>
#include <hip/hip_bf16.h>
#include <math.h>

// Problem: B=32, H=64, W=64, C_IN=384, C_HID=128
// conv3x3(pad1)+b1 -> relu -> conv1x1+b2 -> sigmoid, NHWC fp32.
// Implicit GEMM: M=pixels(131072), N=128, K=9*384=3456 (o-major, 12 chunks of 32 per offset).

typedef __attribute__((ext_vector_type(8))) unsigned short ushort8;
typedef __attribute__((ext_vector_type(8))) __bf16 bf16x8;
typedef __attribute__((ext_vector_type(4))) float floatx4;
typedef __attribute__((ext_vector_type(4))) unsigned int uintx4;

static __device__ __forceinline__ unsigned short f2bf(float f) {
  union { float f; unsigned int u; } x; x.f = f;
  unsigned int u = x.u;
  unsigned int r = (u + 0x7fffu + ((u >> 16) & 1u)) >> 16;  // RNE
  return (unsigned short)r;
}

// Transpose W1 (3,3,384,128 HWIO, fp32) -> bf16 blocks W1b[kk][n][c], kk = o*12+chunk,
// n=0..127, c=0..31 (c contiguous so conv kernel B-staging is 16B-coalesced copies).
__global__ void prep_w1_kernel(const float* __restrict__ W1,
                               unsigned short* __restrict__ W1b) {
  __shared__ unsigned short tile[32 * 128];
  const int kk = blockIdx.x;            // 0..107
  const int o = kk / 12;
  const int chunk = kk - o * 12;
  const float* src = W1 + (o * 384 + chunk * 32) * 128;  // [c][n], n contiguous
  const int t = threadIdx.x;
#pragma unroll
  for (int i = 0; i < 16; ++i) {
    int idx = t + i * 256;              // idx = c*128+n
    int c = idx >> 7;
    int n = idx & 127;
    tile[n * 32 + c] = f2bf(src[idx]);  // coalesced read, transposed LDS write
  }
  __syncthreads();
  unsigned short* dst = W1b + kk * 4096;
#pragma unroll
  for (int i = 0; i < 16; ++i) {
    int idx = t + i * 256;
    dst[idx] = tile[idx];               // coalesced write, layout [n][c]
  }
}

__global__ __launch_bounds__(256) void conv_fused_kernel(
    const float* __restrict__ x, const unsigned short* __restrict__ W1b,
    const float* __restrict__ b1, const float* __restrict__ W2,
    const float* __restrict__ b2, float* __restrict__ out) {
  // LDS: A tile [64 px][40] bf16 (pad 32->40: 2-way bank conflicts only),
  //      B tile [128 n][40] bf16, epilogue partials [64 px][4 waves].
  __shared__ unsigned short Alds[64 * 40];
  __shared__ unsigned short Blds[128 * 40];
  __shared__ float hsum[64 * 4];

  const int t = threadIdx.x;
  const int w = t >> 6;        // wave 0..3 -> n block [32w, 32w+32)
  const int lane = t & 63;
  const int g = lane >> 4;     // quad
  const int lr = lane & 15;

  const int img = blockIdx.x >> 6;       // 32 images
  const int tileId = blockIdx.x & 63;    // 8x8 tiles of 8x8 pixels
  const int ty0 = (tileId >> 3) << 3;
  const int tx0 = (tileId & 7) << 3;

  // A staging: thread -> (pixel ap, channel-sub ac): 4 threads x 8ch per pixel
  const int ap = t >> 2;          // 0..63
  const int ac = (t & 3) << 3;    // 0,8,16,24
  const int apy = ap >> 3;
  const int apx = ap & 7;

  // B staging: thread -> (row bn, 16-elem half bo): 2 threads x 32B per n-row
  const int bn = t >> 1;          // 0..127
  const int bo = (t & 1) << 4;    // 0,16 (elements)

  floatx4 acc[4][2] = {};  // [mi][ni], D row = mi*16 + g*4 + r, col = 32w+16ni+lr

  const float b1v0 = b1[w * 32 + lr];
  const float b1v1 = b1[w * 32 + 16 + lr];
  const float w2v0 = W2[w * 32 + lr];
  const float w2v1 = W2[w * 32 + 16 + lr];

  const unsigned short* qptr = W1b + (bn << 5) + bo;  // advances 4096/kstep

  for (int o = 0; o < 9; ++o) {
    const int oy = o / 3;
    const int ox = o - oy * 3;
    const int iy = ty0 + apy + oy - 1;
    const int ix = tx0 + apx + ox - 1;
    const bool valid = ((unsigned)iy < 64u) && ((unsigned)ix < 64u);
    const float* abase =
        x + ((((img << 6) + iy) << 6) + ix) * 384 + ac;  // + chunk*32 per step

    for (int chunk = 0; chunk < 12; ++chunk) {
      // ---- global loads (before barrier; convert fp32->bf16 inline) ----
      ushort8 a8;
      if (valid) {
        const float* p = abase + (chunk << 5);
        float4 v0 = *(const float4*)p;
        float4 v1 = *(const float4*)(p + 4);
        a8[0] = f2bf(v0.x); a8[1] = f2bf(v0.y);
        a8[2] = f2bf(v0.z); a8[3] = f2bf(v0.w);
        a8[4] = f2bf(v1.x); a8[5] = f2bf(v1.y);
        a8[6] = f2bf(v1.z); a8[7] = f2bf(v1.w);
      } else {
        a8 = (ushort8)0;
      }
      uintx4 bv0 = *(const uintx4*)qptr;
      uintx4 bv1 = *(const uintx4*)(qptr + 8);
      qptr += 4096;

      __syncthreads();  // previous iter's frag reads done
      *(ushort8*)&Alds[ap * 40 + ac] = a8;
      *(uintx4*)&Blds[bn * 40 + bo] = bv0;
      *(uintx4*)&Blds[bn * 40 + bo + 8] = bv1;
      __syncthreads();

      // ---- fragments: A[m=lr][k=g*8+j], B stored [n][k]: row 32w+16ni+lr ----
      bf16x8 afrag[4], bfrag[2];
#pragma unroll
      for (int ni = 0; ni < 2; ++ni)
        bfrag[ni] = *(const bf16x8*)&Blds[(w * 32 + ni * 16 + lr) * 40 + g * 8];
#pragma unroll
      for (int mi = 0; mi < 4; ++mi)
        afrag[mi] = *(const bf16x8*)&Alds[(mi * 16 + lr) * 40 + g * 8];
#pragma unroll
      for (int mi = 0; mi < 4; ++mi)
#pragma unroll
        for (int ni = 0; ni < 2; ++ni)
          acc[mi][ni] = __builtin_amdgcn_mfma_f32_16x16x32_bf16(
              afrag[mi], bfrag[ni], acc[mi][ni], 0, 0, 0);
    }
  }

  // ---- epilogue: bias+relu, conv1x1 (reduce over n), sigmoid ----
#pragma unroll
  for (int mi = 0; mi < 4; ++mi) {
#pragma unroll
    for (int r = 0; r < 4; ++r) {
      float h0 = fmaxf(acc[mi][0][r] + b1v0, 0.0f);
      float h1 = fmaxf(acc[mi][1][r] + b1v1, 0.0f);
      float v = h0 * w2v0 + h1 * w2v1;
      // reduce across the 16 lanes (lr) sharing pixel m
      v += __shfl_xor(v, 1);
      v += __shfl_xor(v, 2);
      v += __shfl_xor(v, 4);
      v += __shfl_xor(v, 8);
      if (lr == 0) {
        int m = mi * 16 + g * 4 + r;
        hsum[m * 4 + w] = v;
      }
    }
  }
  __syncthreads();
  if (t < 64) {
    float s = hsum[t * 4 + 0] + hsum[t * 4 + 1] + hsum[t * 4 + 2] +
              hsum[t * 4 + 3] + b2[0];
    float sig = 1.0f / (1.0f + expf(-s));
    int py = t >> 3, px = t & 7;
    out[((((img << 6) + ty0 + py) << 6) + tx0 + px)] = sig;
  }
}

extern "C" void kernel_launch(void* const* d_in, const int* in_sizes, int n_in,
                              void* d_out, int out_size, void* d_ws, size_t ws_size,
                              hipStream_t stream) {
  const float* x  = (const float*)d_in[0];   // (32,64,64,384)
  const float* W1 = (const float*)d_in[1];   // (3,3,384,128)
  const float* b1 = (const float*)d_in[2];   // (128)
  const float* W2 = (const float*)d_in[3];   // (128)
  const float* b2 = (const float*)d_in[4];   // (1)
  float* out = (float*)d_out;                // (32,64,64,1)
  unsigned short* W1b = (unsigned short*)d_ws;  // 108*4096*2 = 884736 B

  prep_w1_kernel<<<108, 256, 0, stream>>>(W1, W1b);
  conv_fused_kernel<<<2048, 256, 0, stream>>>(x, W1b, b1, W2, b2, out);
}

// Round 2
// 379.767 us; speedup vs baseline: 1.4046x; 1.4046x over previous
//
#include <hip/hip_runtime.h>
#include <math.h>

// B=32, H=64, W=64, C_IN=384, C_HID=128
// conv3x3(pad1)+b1 -> relu -> conv1x1+b2 -> sigmoid, NHWC fp32.
// Implicit GEMM, halo-LDS structure:
//   per block: 8x8 output pixels (M=64), N=128, K=9*384.
//   chunk loop (12 x 32 channels): stage 10x10 halo x 32ch bf16 into LDS once,
//   then 9 taps read A-frags from LDS; B-frags direct global->reg (L2-resident).

typedef __attribute__((ext_vector_type(8))) unsigned short ushort8;
typedef __attribute__((ext_vector_type(8))) __bf16 bf16x8;
typedef __attribute__((ext_vector_type(4))) float floatx4;

static __device__ __forceinline__ unsigned short f2bf(float f) {
  union { float f; unsigned int u; } x; x.f = f;
  return (unsigned short)((x.u + 0x8000u) >> 16);  // round-to-nearest (ties away)
}
static __device__ __forceinline__ unsigned short f2bf_rne(float f) {
  union { float f; unsigned int u; } x; x.f = f;
  unsigned int u = x.u;
  return (unsigned short)((u + 0x7fffu + ((u >> 16) & 1u)) >> 16);
}

// W1 (3,3,384,128 HWIO fp32) -> bf16 W1b[kk][n][c], kk=o*12+chunk, n=0..127, c=0..31.
__global__ void prep_w1_kernel(const float* __restrict__ W1,
                               unsigned short* __restrict__ W1b) {
  __shared__ unsigned short tile[32 * 128];
  const int kk = blockIdx.x;            // 0..107
  const int o = kk / 12;
  const int chunk = kk - o * 12;
  const float* src = W1 + (o * 384 + chunk * 32) * 128;  // [c][n], n contiguous
  const int t = threadIdx.x;
#pragma unroll
  for (int i = 0; i < 16; ++i) {
    int idx = t + i * 256;              // idx = c*128+n
    int c = idx >> 7;
    int n = idx & 127;
    tile[n * 32 + c] = f2bf_rne(src[idx]);
  }
  __syncthreads();
  unsigned short* dst = W1b + kk * 4096;
#pragma unroll
  for (int i = 0; i < 16; ++i) {
    int idx = t + i * 256;
    dst[idx] = tile[idx];
  }
}

__global__ __launch_bounds__(256) void conv_fused_kernel(
    const float* __restrict__ x, const unsigned short* __restrict__ W1b,
    const float* __restrict__ b1, const float* __restrict__ W2,
    const float* __restrict__ b2, float* __restrict__ out) {
  // Halo tile: 10x10 px, 32 ch, padded stride 40 elems (80 B -> <=2-way conflicts, free)
  __shared__ alignas(16) unsigned short Ah[100 * 40];  // 8000 B
  __shared__ float hsum[64 * 4];

  const int t = threadIdx.x;
  const int w = t >> 6;        // wave 0..3 -> n block [32w, 32w+32)
  const int lane = t & 63;
  const int g = lane >> 4;     // quad
  const int lr = lane & 15;

  const int img = blockIdx.x >> 6;       // 32 images
  const int tileId = blockIdx.x & 63;    // 8x8 tiles of 8x8 pixels
  const int ty0 = (tileId >> 3) << 3;
  const int tx0 = (tileId & 7) << 3;

  // ---- A-halo staging plan: 400 items (px 0..99 x sub 0..3), 8 ch per item ----
  // item0 = t, item1 = t+256 (active if t<144)
  const int px0 = t >> 2, sub0 = t & 3;
  const int hy0 = (px0 * 205) >> 11;     // /10
  const int hx0 = px0 - hy0 * 10;
  const int iy0 = ty0 + hy0 - 1, ix0 = tx0 + hx0 - 1;
  const bool v0 = ((unsigned)iy0 < 64u) && ((unsigned)ix0 < 64u);
  const float* ab0 =
      x + ((((img << 6) + iy0) << 6) + ix0) * 384 + sub0 * 8;

  const int i1 = t + 256;
  const bool act1 = i1 < 400;
  const int px1 = i1 >> 2, sub1 = i1 & 3;
  const int hy1 = (px1 * 205) >> 11;
  const int hx1 = px1 - hy1 * 10;
  const int iy1 = ty0 + hy1 - 1, ix1 = tx0 + hx1 - 1;
  const bool v1 = act1 && ((unsigned)iy1 < 64u) && ((unsigned)ix1 < 64u);
  const float* ab1 =
      x + ((((img << 6) + iy1) << 6) + ix1) * 384 + sub1 * 8;

  // B frag base (elems): row n = w*32 + lr (+16 for ni=1), k-sub = g*8
  const int boff = ((w * 32 + lr) << 5) + (g << 3);
  // A frag base (elems) for mi=0,o=0: pixel (lr>>3, lr&7) in halo coords + quad k-sub
  const int aoffb = ((lr >> 3) * 10 + (lr & 7)) * 40 + (g << 3);

  floatx4 acc[4][2] = {};  // D: row = mi*16 + g*4 + r, col = w*32 + ni*16 + lr

  const float b1v0 = b1[w * 32 + lr];
  const float b1v1 = b1[w * 32 + 16 + lr];
  const float w2v0 = W2[w * 32 + lr];
  const float w2v1 = W2[w * 32 + 16 + lr];

  for (int chunk = 0; chunk < 12; ++chunk) {
    // ---- global loads for halo staging (issue before barrier) ----
    ushort8 a0 = (ushort8)0, a1 = (ushort8)0;
    if (v0) {
      const float* p = ab0 + (chunk << 5);
      float4 q0 = *(const float4*)p;
      float4 q1 = *(const float4*)(p + 4);
      a0[0] = f2bf(q0.x); a0[1] = f2bf(q0.y); a0[2] = f2bf(q0.z); a0[3] = f2bf(q0.w);
      a0[4] = f2bf(q1.x); a0[5] = f2bf(q1.y); a0[6] = f2bf(q1.z); a0[7] = f2bf(q1.w);
    }
    if (v1) {
      const float* p = ab1 + (chunk << 5);
      float4 q0 = *(const float4*)p;
      float4 q1 = *(const float4*)(p + 4);
      a1[0] = f2bf(q0.x); a1[1] = f2bf(q0.y); a1[2] = f2bf(q0.z); a1[3] = f2bf(q0.w);
      a1[4] = f2bf(q1.x); a1[5] = f2bf(q1.y); a1[6] = f2bf(q1.z); a1[7] = f2bf(q1.w);
    }

    __syncthreads();  // previous chunk's LDS reads complete
    *(ushort8*)&Ah[px0 * 40 + sub0 * 8] = a0;
    if (act1) *(ushort8*)&Ah[px1 * 40 + sub1 * 8] = a1;
    __syncthreads();

    // ---- 9 taps from LDS; B direct from global (L2-resident) ----
#pragma unroll
    for (int o = 0; o < 9; ++o) {
      const int oy = o / 3, ox = o - oy * 3;
      const unsigned short* bp = W1b + ((o * 12 + chunk) << 12) + boff;
      bf16x8 bf0 = *(const bf16x8*)bp;
      bf16x8 bf1 = *(const bf16x8*)(bp + 512);
#pragma unroll
      for (int mi = 0; mi < 4; ++mi) {
        // pixel m = mi*16+lr -> (py,px) = (mi*2 + (lr>>3), lr&7); tap shifts (+oy,+ox)
        const bf16x8 af =
            *(const bf16x8*)&Ah[aoffb + (mi * 2 + oy) * 400 + ox * 40];
        acc[mi][0] = __builtin_amdgcn_mfma_f32_16x16x32_bf16(af, bf0, acc[mi][0], 0, 0, 0);
        acc[mi][1] = __builtin_amdgcn_mfma_f32_16x16x32_bf16(af, bf1, acc[mi][1], 0, 0, 0);
      }
    }
  }

  // ---- epilogue: bias+relu, conv1x1 reduce over n, sigmoid ----
#pragma unroll
  for (int mi = 0; mi < 4; ++mi) {
#pragma unroll
    for (int r = 0; r < 4; ++r) {
      float h0 = fmaxf(acc[mi][0][r] + b1v0, 0.0f);
      float h1 = fmaxf(acc[mi][1][r] + b1v1, 0.0f);
      float v = h0 * w2v0 + h1 * w2v1;
      v += __shfl_xor(v, 1);
      v += __shfl_xor(v, 2);
      v += __shfl_xor(v, 4);
      v += __shfl_xor(v, 8);
      if (lr == 0) {
        int m = mi * 16 + g * 4 + r;
        hsum[m * 4 + w] = v;
      }
    }
  }
  __syncthreads();
  if (t < 64) {
    float s = hsum[t * 4 + 0] + hsum[t * 4 + 1] + hsum[t * 4 + 2] +
              hsum[t * 4 + 3] + b2[0];
    float sig = 1.0f / (1.0f + expf(-s));
    int py = t >> 3, px = t & 7;
    out[((((img << 6) + ty0 + py) << 6) + tx0 + px)] = sig;
  }
}

extern "C" void kernel_launch(void* const* d_in, const int* in_sizes, int n_in,
                              void* d_out, int out_size, void* d_ws, size_t ws_size,
                              hipStream_t stream) {
  const float* x  = (const float*)d_in[0];   // (32,64,64,384)
  const float* W1 = (const float*)d_in[1];   // (3,3,384,128)
  const float* b1 = (const float*)d_in[2];   // (128)
  const float* W2 = (const float*)d_in[3];   // (128)
  const float* b2 = (const float*)d_in[4];   // (1)
  float* out = (float*)d_out;                // (32,64,64,1)
  unsigned short* W1b = (unsigned short*)d_ws;  // 108*4096*2 = 884736 B

  prep_w1_kernel<<<108, 256, 0, stream>>>(W1, W1b);
  conv_fused_kernel<<<2048, 256, 0, stream>>>(x, W1b, b1, W2, b2, out);
}

// Round 3
// 346.611 us; speedup vs baseline: 1.5389x; 1.0957x over previous
//
#include <hip/hip_runtime.h>
#include <hip/hip_bf16.h>
#include <math.h>

// B=32, H=64, W=64, C_IN=384, C_HID=128
// conv3x3(pad1)+b1 -> relu -> conv1x1+b2 -> sigmoid, NHWC fp32.
// Implicit GEMM, halo-LDS, tap-sharing structure:
//   per block: 16x8 output pixels (M=128), N=128, K=9*384.
//   chunk loop (12 x 32 ch): stage 10x18 halo x 32ch bf16 into LDS (register-
//   prefetched one chunk ahead), then loop ox -> halo-row h -> oy: each A-frag
//   ds_read feeds up to 6 MFMAs (3 oy x 2 ni). B-frags direct global->reg (L2).

typedef __attribute__((ext_vector_type(8))) unsigned short ushort8;
typedef __attribute__((ext_vector_type(8))) __bf16 bf16x8;
typedef __attribute__((ext_vector_type(4))) float floatx4;

static __device__ __forceinline__ unsigned short f2bf_rne(float f) {
  union { float f; unsigned int u; } x; x.f = f;
  unsigned int u = x.u;
  return (unsigned short)((u + 0x7fffu + ((u >> 16) & 1u)) >> 16);
}

static __device__ __forceinline__ ushort8 pack8(const float* v) {
  ushort8 r;
#pragma unroll
  for (int i = 0; i < 4; ++i) {
    __hip_bfloat162 p = __float22bfloat162_rn(make_float2(v[2 * i], v[2 * i + 1]));
    union { __hip_bfloat162 b; unsigned int u; } c;
    c.b = p;
    r[2 * i] = (unsigned short)(c.u & 0xffffu);
    r[2 * i + 1] = (unsigned short)(c.u >> 16);
  }
  return r;
}

// W1 (3,3,384,128 HWIO fp32) -> bf16 W1b[kk][n][c], kk=o*12+chunk, n=0..127, c=0..31.
__global__ void prep_w1_kernel(const float* __restrict__ W1,
                               unsigned short* __restrict__ W1b) {
  __shared__ unsigned short tile[32 * 128];
  const int kk = blockIdx.x;            // 0..107
  const int o = kk / 12;
  const int chunk = kk - o * 12;
  const float* src = W1 + (o * 384 + chunk * 32) * 128;  // [c][n], n contiguous
  const int t = threadIdx.x;
#pragma unroll
  for (int i = 0; i < 16; ++i) {
    int idx = t + i * 256;              // idx = c*128+n
    int c = idx >> 7;
    int n = idx & 127;
    tile[n * 32 + c] = f2bf_rne(src[idx]);
  }
  __syncthreads();
  unsigned short* dst = W1b + kk * 4096;
#pragma unroll
  for (int i = 0; i < 16; ++i) {
    int idx = t + i * 256;
    dst[idx] = tile[idx];
  }
}

__global__ __launch_bounds__(256) void conv_fused_kernel(
    const float* __restrict__ x, const unsigned short* __restrict__ W1b,
    const float* __restrict__ b1, const float* __restrict__ W2,
    const float* __restrict__ b2, float* __restrict__ out) {
  // Halo: 10 rows x 18 cols x 32 ch bf16, pixel stride 40 elems (80 B).
  __shared__ alignas(16) unsigned short Ah[180 * 40];  // 14400 B
  __shared__ float hsum[128 * 4];                      // 2048 B

  const int t = threadIdx.x;
  const int w = t >> 6;        // wave 0..3 -> n block [32w, 32w+32)
  const int lane = t & 63;
  const int g = lane >> 4;     // quad
  const int lr = lane & 15;

  const int img = blockIdx.x >> 5;       // 32 images
  const int tileId = blockIdx.x & 31;    // 8x4 grid of 8(tall)x16(wide) tiles
  const int ty0 = (tileId >> 2) << 3;
  const int tx0 = (tileId & 3) << 4;

  // ---- staging plan: 720 items (halo px 0..179 x sub 0..3), 8 ch each ----
  // items: t, t+256, t+512(active if t<208)
  int svalid[3];
  const float* sptr[3];
  int sloff[3];
  const bool act2 = t < 208;
#pragma unroll
  for (int j = 0; j < 3; ++j) {
    int i = t + j * 256;
    int px = i >> 2, sub = i & 3;
    int hy = (px * 57) >> 10;            // px / 18 for px < 1024
    int hx = px - hy * 18;
    int iy = ty0 + hy - 1, ix = tx0 + hx - 1;
    int v = ((unsigned)iy < 64u) && ((unsigned)ix < 64u);
    if (j == 2 && !act2) v = 0;
    svalid[j] = v;
    int iyc = v ? iy : 0, ixc = v ? ix : 0;
    sptr[j] = x + ((((img << 6) + iyc) << 6) + ixc) * 384 + sub * 8;
    sloff[j] = px * 40 + sub * 8;
  }

  // B frag offset (elems): row n = w*32 + lr (+16 for ni=1), k-sub = g*8
  const int boff = ((w * 32 + lr) << 5) + (g << 3);
  // A frag lane part (elems): col lr, quad k-sub
  const int aoffl = lr * 40 + (g << 3);

  floatx4 acc[8][2] = {};  // D: pixel row mi, col lr; ch n = w*32+ni*16+lr

  const float b1v0 = b1[w * 32 + lr];
  const float b1v1 = b1[w * 32 + 16 + lr];
  const float w2v0 = W2[w * 32 + lr];
  const float w2v1 = W2[w * 32 + 16 + lr];

  float sreg[3][8];

  // ---- prologue: load chunk 0 into regs ----
#pragma unroll
  for (int j = 0; j < 3; ++j) {
    if (svalid[j]) {
      *(float4*)&sreg[j][0] = *(const float4*)sptr[j];
      *(float4*)&sreg[j][4] = *(const float4*)(sptr[j] + 4);
    } else {
#pragma unroll
      for (int e = 0; e < 8; ++e) sreg[j][e] = 0.0f;
    }
  }

  for (int chunk = 0; chunk < 12; ++chunk) {
    __syncthreads();  // previous chunk's LDS reads complete
    *(ushort8*)&Ah[sloff[0]] = pack8(sreg[0]);
    *(ushort8*)&Ah[sloff[1]] = pack8(sreg[1]);
    if (act2) *(ushort8*)&Ah[sloff[2]] = pack8(sreg[2]);
    __syncthreads();

    // ---- prefetch next chunk into regs (completes during compute) ----
    if (chunk < 11) {
      const int off = (chunk + 1) << 5;
#pragma unroll
      for (int j = 0; j < 3; ++j) {
        if (svalid[j]) {
          *(float4*)&sreg[j][0] = *(const float4*)(sptr[j] + off);
          *(float4*)&sreg[j][4] = *(const float4*)(sptr[j] + off + 4);
        }
      }
    }

    // ---- compute: ox -> 6 B-frags; h -> A-frag feeds (mi = h - oy) ----
#pragma unroll
    for (int ox = 0; ox < 3; ++ox) {
      bf16x8 bf[3][2];
#pragma unroll
      for (int oy = 0; oy < 3; ++oy) {
        const unsigned short* bp =
            W1b + ((((oy * 3 + ox) * 12 + chunk) << 12)) + boff;
        bf[oy][0] = *(const bf16x8*)bp;
        bf[oy][1] = *(const bf16x8*)(bp + 512);
      }
#pragma unroll
      for (int h = 0; h < 10; ++h) {
        const bf16x8 af = *(const bf16x8*)&Ah[h * 720 + ox * 40 + aoffl];
#pragma unroll
        for (int oy = 0; oy < 3; ++oy) {
          const int mi = h - oy;
          if (mi >= 0 && mi < 8) {
            acc[mi][0] = __builtin_amdgcn_mfma_f32_16x16x32_bf16(
                af, bf[oy][0], acc[mi][0], 0, 0, 0);
            acc[mi][1] = __builtin_amdgcn_mfma_f32_16x16x32_bf16(
                af, bf[oy][1], acc[mi][1], 0, 0, 0);
          }
        }
      }
    }
  }

  // ---- epilogue: bias+relu, conv1x1 reduce over n, sigmoid ----
#pragma unroll
  for (int mi = 0; mi < 8; ++mi) {
#pragma unroll
    for (int r = 0; r < 4; ++r) {
      float h0 = fmaxf(acc[mi][0][r] + b1v0, 0.0f);
      float h1 = fmaxf(acc[mi][1][r] + b1v1, 0.0f);
      float v = h0 * w2v0 + h1 * w2v1;
      v += __shfl_xor(v, 1);
      v += __shfl_xor(v, 2);
      v += __shfl_xor(v, 4);
      v += __shfl_xor(v, 8);
      if (lr == 0) {
        int m = mi * 16 + g * 4 + r;  // pixel: row mi, col g*4+r? no: see below
        hsum[m * 4 + w] = v;
      }
    }
  }
  __syncthreads();
  if (t < 128) {
    float s = hsum[t * 4 + 0] + hsum[t * 4 + 1] + hsum[t * 4 + 2] +
              hsum[t * 4 + 3] + b2[0];
    float sig = 1.0f / (1.0f + expf(-s));
    // m = mi*16 + (g*4+r): pixel row = mi = m>>4? No — D row index g*4+r IS the
    // M index within the 16-row frag; our frag m-index = pixel col (px=lr is
    // A's m). Wait: A[m=lr] -> m is the MFMA row = output pixel COLUMN here.
    // m = mi*16 + g*4 + r encodes: pixel row = mi, pixel col = g*4+r.
    int prow = t >> 4, pcol = t & 15;
    out[((((img << 6) + ty0 + prow) << 6) + tx0 + pcol)] = sig;
  }
}

extern "C" void kernel_launch(void* const* d_in, const int* in_sizes, int n_in,
                              void* d_out, int out_size, void* d_ws, size_t ws_size,
                              hipStream_t stream) {
  const float* x  = (const float*)d_in[0];   // (32,64,64,384)
  const float* W1 = (const float*)d_in[1];   // (3,3,384,128)
  const float* b1 = (const float*)d_in[2];   // (128)
  const float* W2 = (const float*)d_in[3];   // (128)
  const float* b2 = (const float*)d_in[4];   // (1)
  float* out = (float*)d_out;                // (32,64,64,1)
  unsigned short* W1b = (unsigned short*)d_ws;  // 108*4096*2 = 884736 B

  prep_w1_kernel<<<108, 256, 0, stream>>>(W1, W1b);
  conv_fused_kernel<<<1024, 256, 0, stream>>>(x, W1b, b1, W2, b2, out);
}